// Round 1
// baseline (1612.099 us; speedup 1.0000x reference)
//
#include <hip/hip_runtime.h>

#define NPTS (4 * 16384)      // B*N = 65536 points
#define DD 512                // feature dim
#define NSEG 8192             // B*C segments
#define TILE 32               // points per block
#define HGEO_OFF (NPTS * DD)  // h_geo offset in d_out (33554432)

// ---------------- Kernel A: per-segment count + sum(pos) ----------------
__global__ __launch_bounds__(256) void seg_sum_kernel(
    const float* __restrict__ pos, const int* __restrict__ cid,
    float* __restrict__ acc /* [4*NSEG]: cnt, sx, sy, sz */) {
  const int i = blockIdx.x * 256 + threadIdx.x;  // point index, grid sized exactly
  const int b = i >> 14;                          // N = 16384
  const int seg = (b << 11) + cid[i];             // C = 2048
  atomicAdd(&acc[seg], 1.0f);
  atomicAdd(&acc[NSEG + seg],     pos[i * 3 + 0]);
  atomicAdd(&acc[2 * NSEG + seg], pos[i * 3 + 1]);
  atomicAdd(&acc[3 * NSEG + seg], pos[i * 3 + 2]);
}

// ---------------- Kernel B: fused LPE block ----------------
// Per block: 32 points. Compute local_p/norm, then for each MLP:
//   hidden[32][512] in LDS (relu(x @ W_first + b)), then register-tiled
//   matmul vs the 512x512 second-layer weight, epilogue adds feat + bias.
__global__ __launch_bounds__(256) void lpe_main(
    const float* __restrict__ pos, const float* __restrict__ feat,
    const int* __restrict__ cid,
    const float* __restrict__ w1, const float* __restrict__ b1,
    const float* __restrict__ w2, const float* __restrict__ b2,
    const float* __restrict__ w3, const float* __restrict__ b3,
    const float* __restrict__ w4, const float* __restrict__ b4,
    const float* __restrict__ segacc, float* __restrict__ out) {
  __shared__ float hs[TILE][DD];   // 64 KiB hidden tile (reused by both MLPs)
  __shared__ float lp[TILE][4];    // x, y, z, norm per point

  const int tid = threadIdx.x;
  const int base = blockIdx.x * TILE;

  // ---- per-point local coords (threads 0..31, one point each) ----
  if (tid < TILE) {
    const int pt = base + tid;
    const int b = pt >> 14;
    const int seg = (b << 11) + cid[pt];
    const float c = fmaxf(segacc[seg], 1.0f);
    const float x = pos[pt * 3 + 0] - segacc[NSEG + seg] / c;
    const float y = pos[pt * 3 + 1] - segacc[2 * NSEG + seg] / c;
    const float z = pos[pt * 3 + 2] - segacc[3 * NSEG + seg] / c;
    lp[tid][0] = x; lp[tid][1] = y; lp[tid][2] = z;
    lp[tid][3] = sqrtf(x * x + y * y + z * z);
  }
  __syncthreads();

  const int k0 = tid, k1 = tid + 256;  // hidden units this thread produces

  // Register-tiled matmul: out[p][d] = feat[p][d] + sum_k hs[p][k]*W[k][d] + bias[d]
  auto matmul_store = [&](const float* __restrict__ W,
                          const float* __restrict__ bias,
                          float* __restrict__ outp) {
    const int d0 = tid * 2;  // two consecutive output dims per thread
    float accx[TILE], accy[TILE];
#pragma unroll
    for (int p = 0; p < TILE; ++p) { accx[p] = 0.f; accy[p] = 0.f; }
#pragma unroll 2
    for (int k = 0; k < DD; k += 4) {
      const float2 wv0 = *(const float2*)&W[(k + 0) * DD + d0];
      const float2 wv1 = *(const float2*)&W[(k + 1) * DD + d0];
      const float2 wv2 = *(const float2*)&W[(k + 2) * DD + d0];
      const float2 wv3 = *(const float2*)&W[(k + 3) * DD + d0];
#pragma unroll
      for (int p = 0; p < TILE; ++p) {
        const float4 hv = *(const float4*)&hs[p][k];  // wave-broadcast LDS read
        accx[p] = fmaf(hv.x, wv0.x, accx[p]);
        accy[p] = fmaf(hv.x, wv0.y, accy[p]);
        accx[p] = fmaf(hv.y, wv1.x, accx[p]);
        accy[p] = fmaf(hv.y, wv1.y, accy[p]);
        accx[p] = fmaf(hv.z, wv2.x, accx[p]);
        accy[p] = fmaf(hv.z, wv2.y, accy[p]);
        accx[p] = fmaf(hv.w, wv3.x, accx[p]);
        accy[p] = fmaf(hv.w, wv3.y, accy[p]);
      }
    }
    const float2 bv = *(const float2*)&bias[d0];
#pragma unroll 4
    for (int p = 0; p < TILE; ++p) {
      const int idx = (base + p) * DD + d0;
      const float2 fv = *(const float2*)&feat[idx];
      float2 ov;
      ov.x = fv.x + accx[p] + bv.x;
      ov.y = fv.y + accy[p] + bv.y;
      *(float2*)&outp[idx] = ov;
    }
  };

  // ---- MLP 1: x1 = [local_p, nrm] ; hidden = relu(x1 @ w1 + b1) ----
  {
    const float a0 = w1[k0], a1 = w1[DD + k0], a2 = w1[2 * DD + k0], a3 = w1[3 * DD + k0];
    const float c0 = w1[k1], c1 = w1[DD + k1], c2 = w1[2 * DD + k1], c3 = w1[3 * DD + k1];
    const float bb0 = b1[k0], bb1 = b1[k1];
#pragma unroll 4
    for (int p = 0; p < TILE; ++p) {
      const float x = lp[p][0], y = lp[p][1], z = lp[p][2], n = lp[p][3];
      hs[p][k0] = fmaxf(fmaf(x, a0, fmaf(y, a1, fmaf(z, a2, fmaf(n, a3, bb0)))), 0.f);
      hs[p][k1] = fmaxf(fmaf(x, c0, fmaf(y, c1, fmaf(z, c2, fmaf(n, c3, bb1)))), 0.f);
    }
  }
  __syncthreads();
  matmul_store(w2, b2, out);  // h_pos
  __syncthreads();            // all waves done reading hs before overwrite

  // ---- MLP 2: x2 = [avg(~=0), local_p] ; only w3 rows 3..5 matter ----
  {
    const float a0 = w3[3 * DD + k0], a1 = w3[4 * DD + k0], a2 = w3[5 * DD + k0];
    const float c0 = w3[3 * DD + k1], c1 = w3[4 * DD + k1], c2 = w3[5 * DD + k1];
    const float bb0 = b3[k0], bb1 = b3[k1];
#pragma unroll 4
    for (int p = 0; p < TILE; ++p) {
      const float x = lp[p][0], y = lp[p][1], z = lp[p][2];
      hs[p][k0] = fmaxf(fmaf(x, a0, fmaf(y, a1, fmaf(z, a2, bb0))), 0.f);
      hs[p][k1] = fmaxf(fmaf(x, c0, fmaf(y, c1, fmaf(z, c2, bb1))), 0.f);
    }
  }
  __syncthreads();
  matmul_store(w4, b4, out + HGEO_OFF);  // h_geo
}

extern "C" void kernel_launch(void* const* d_in, const int* in_sizes, int n_in,
                              void* d_out, int out_size, void* d_ws, size_t ws_size,
                              hipStream_t stream) {
  const float* pos  = (const float*)d_in[0];
  const float* feat = (const float*)d_in[1];
  const int*   cid  = (const int*)d_in[2];
  const float* w1 = (const float*)d_in[3];
  const float* b1 = (const float*)d_in[4];
  const float* w2 = (const float*)d_in[5];
  const float* b2 = (const float*)d_in[6];
  const float* w3 = (const float*)d_in[7];
  const float* b3 = (const float*)d_in[8];
  const float* w4 = (const float*)d_in[9];
  const float* b4 = (const float*)d_in[10];
  float* out = (float*)d_out;
  float* segacc = (float*)d_ws;  // 4*NSEG floats = 128 KiB

  hipMemsetAsync(segacc, 0, 4 * NSEG * sizeof(float), stream);
  seg_sum_kernel<<<NPTS / 256, 256, 0, stream>>>(pos, cid, segacc);
  lpe_main<<<NPTS / TILE, 256, 0, stream>>>(pos, feat, cid,
                                            w1, b1, w2, b2, w3, b3, w4, b4,
                                            segacc, out);
}

// Round 2
// 478.790 us; speedup vs baseline: 3.3670x; 3.3670x over previous
//
#include <hip/hip_runtime.h>
#include <hip/hip_bf16.h>

#define NPTS (4 * 16384)       // B*N = 65536
#define DD 512
#define NSEG 8192              // B*C
#define MT 64                  // points per block
#define BK 64                  // k-step
#define HGEO_OFF (NPTS * DD)

typedef __attribute__((ext_vector_type(8))) short short8;   // 8 bf16
typedef __attribute__((ext_vector_type(4))) float f32x4;

__device__ __forceinline__ short f2bf(float f) {
  union { float f; unsigned u; } v{f};
  unsigned r = v.u + 0x7fffu + ((v.u >> 16) & 1u);
  return (short)(r >> 16);
}

// ---------------- Kernel A: per-segment count + sum(pos) ----------------
__global__ __launch_bounds__(256) void seg_sum_kernel(
    const float* __restrict__ pos, const int* __restrict__ cid,
    float* __restrict__ acc) {
  const int i = blockIdx.x * 256 + threadIdx.x;
  const int b = i >> 14;
  const int seg = (b << 11) + cid[i];
  atomicAdd(&acc[seg], 1.0f);
  atomicAdd(&acc[NSEG + seg],     pos[i * 3 + 0]);
  atomicAdd(&acc[2 * NSEG + seg], pos[i * 3 + 1]);
  atomicAdd(&acc[3 * NSEG + seg], pos[i * 3 + 2]);
}

// ------------- Kernel B: transpose + bf16 convert of w2, w4 -------------
// dst[n][k] = (bf16) src[k][n]
__global__ __launch_bounds__(256) void wt_cvt(
    const float* __restrict__ w2, const float* __restrict__ w4,
    __hip_bfloat16* __restrict__ wt2, __hip_bfloat16* __restrict__ wt4) {
  __shared__ float t[32][33];
  const int b = blockIdx.x;
  const float* src = (b & 1) ? w4 : w2;
  __hip_bfloat16* dst = (b & 1) ? wt4 : wt2;
  const int tile = b >> 1;                 // 0..255
  const int tr = tile >> 4, tc = tile & 15;
  const int i = threadIdx.x >> 5, j = threadIdx.x & 31;
#pragma unroll
  for (int ii = 0; ii < 32; ii += 8)
    t[i + ii][j] = src[(tr * 32 + i + ii) * DD + tc * 32 + j];
  __syncthreads();
#pragma unroll
  for (int ii = 0; ii < 32; ii += 8)
    dst[(tc * 32 + i + ii) * DD + tr * 32 + j] = __float2bfloat16(t[j][i + ii]);
}

// ---------------- Kernel C: fused MFMA LPE ----------------
// Per block: 64 points, full N=512. A (hidden) computed on the fly per
// k-step into swizzled LDS; B (W^T k-tile) staged via global_load_lds with
// pre-swizzled source. acc[4 m-frags][8 n-frags] per thread.
template <int NR>
__device__ __forceinline__ void gemm_phase(
    const int tid, const int wave, const int lane, const int base,
    const float (*lps)[4], short* __restrict__ As, short* __restrict__ Bs,
    const float* __restrict__ wfirst, const float* __restrict__ bfirst,
    const __hip_bfloat16* __restrict__ WT, const float* __restrict__ bsec,
    const float* __restrict__ feat, float* __restrict__ outp) {
  f32x4 acc[4][8];
#pragma unroll
  for (int a = 0; a < 4; ++a)
#pragma unroll
    for (int b = 0; b < 8; ++b) acc[a][b] = (f32x4)0.f;

  // per-lane B-staging source: row n = wave*128 + i*8 + (lane>>3),
  // chunk swizzle c' = (lane&7) ^ ((lane>>3)&7)  (involution, matches read)
  const int swz_elem = (((lane & 7) ^ ((lane >> 3) & 7)) << 3);
  const __hip_bfloat16* gbase =
      WT + (size_t)(wave * 128 + (lane >> 3)) * DD + swz_elem;

  for (int ks = 0; ks < DD / BK; ++ks) {
    __syncthreads();  // everyone done reading previous tiles
    // ---- stage B k-tile: 16 x global_load_lds(16B) per thread ----
    const __hip_bfloat16* g = gbase + ks * BK;
#pragma unroll
    for (int i = 0; i < 16; ++i) {
      __builtin_amdgcn_global_load_lds(
          (const __attribute__((address_space(1))) unsigned int*)(g + (size_t)(i * 8) * DD),
          (__attribute__((address_space(3))) unsigned int*)(Bs + (wave * 16 + i) * 512),
          16, 0, 0);
    }
    // ---- compute A k-tile (hidden) into swizzled LDS ----
#pragma unroll
    for (int pass = 0; pass < 2; ++pass) {
      const int o = tid + pass * 256;
      const int m = o >> 3, c = o & 7;
      const int kk0 = ks * BK + c * 8;
      const float x = lps[m][0], y = lps[m][1], z = lps[m][2], w = lps[m][3];
      short8 hv;
#pragma unroll
      for (int j = 0; j < 8; j += 4) {
        const float4 a0 = *(const float4*)&wfirst[0 * DD + kk0 + j];
        const float4 a1 = *(const float4*)&wfirst[1 * DD + kk0 + j];
        const float4 a2 = *(const float4*)&wfirst[2 * DD + kk0 + j];
        const float4 bb = *(const float4*)&bfirst[kk0 + j];
        float h0 = fmaf(x, a0.x, fmaf(y, a1.x, fmaf(z, a2.x, bb.x)));
        float h1 = fmaf(x, a0.y, fmaf(y, a1.y, fmaf(z, a2.y, bb.y)));
        float h2 = fmaf(x, a0.z, fmaf(y, a1.z, fmaf(z, a2.z, bb.z)));
        float h3 = fmaf(x, a0.w, fmaf(y, a1.w, fmaf(z, a2.w, bb.w)));
        if (NR == 4) {
          const float4 a3 = *(const float4*)&wfirst[3 * DD + kk0 + j];
          h0 = fmaf(w, a3.x, h0); h1 = fmaf(w, a3.y, h1);
          h2 = fmaf(w, a3.z, h2); h3 = fmaf(w, a3.w, h3);
        }
        hv[j + 0] = f2bf(fmaxf(h0, 0.f));
        hv[j + 1] = f2bf(fmaxf(h1, 0.f));
        hv[j + 2] = f2bf(fmaxf(h2, 0.f));
        hv[j + 3] = f2bf(fmaxf(h3, 0.f));
      }
      *(short8*)&As[m * BK + ((c ^ (m & 7)) << 3)] = hv;
    }
    __syncthreads();  // tiles ready
    // ---- fragments + MFMA ----
#pragma unroll
    for (int ksub = 0; ksub < 2; ++ksub) {
      const int kb = ksub * 4 + (lane >> 4);
      short8 af[4], bfr[8];
#pragma unroll
      for (int mf = 0; mf < 4; ++mf) {
        const int m = mf * 16 + (lane & 15);
        af[mf] = *(const short8*)&As[m * BK + ((kb ^ (m & 7)) << 3)];
      }
#pragma unroll
      for (int nf = 0; nf < 8; ++nf) {
        const int n = wave * 128 + nf * 16 + (lane & 15);
        bfr[nf] = *(const short8*)&Bs[n * BK + ((kb ^ (n & 7)) << 3)];
      }
#pragma unroll
      for (int mf = 0; mf < 4; ++mf)
#pragma unroll
        for (int nf = 0; nf < 8; ++nf)
          acc[mf][nf] = __builtin_amdgcn_mfma_f32_16x16x32_bf16(
              af[mf], bfr[nf], acc[mf][nf], 0, 0, 0);
    }
  }
  // ---- epilogue: out = feat + acc + bias ----
#pragma unroll
  for (int mf = 0; mf < 4; ++mf) {
    const int r = base + mf * 16 + ((lane >> 4) << 2);
#pragma unroll
    for (int nf = 0; nf < 8; ++nf) {
      const int cg = wave * 128 + nf * 16 + (lane & 15);
      const float bsv = bsec[cg];
#pragma unroll
      for (int j = 0; j < 4; ++j) {
        const size_t idx = (size_t)(r + j) * DD + cg;
        outp[idx] = feat[idx] + acc[mf][nf][j] + bsv;
      }
    }
  }
}

__global__ __launch_bounds__(256, 2) void lpe_mfma(
    const float* __restrict__ pos, const float* __restrict__ feat,
    const int* __restrict__ cid,
    const float* __restrict__ w1, const float* __restrict__ b1,
    const float* __restrict__ b2,
    const float* __restrict__ w3, const float* __restrict__ b3,
    const float* __restrict__ b4,
    const float* __restrict__ segacc,
    const __hip_bfloat16* __restrict__ wt2,
    const __hip_bfloat16* __restrict__ wt4,
    float* __restrict__ out) {
  __shared__ float lps[MT][4];
  __shared__ __align__(16) short Bs[DD * BK];  // 64 KiB, [n][kk] swizzled
  __shared__ __align__(16) short As[MT * BK];  // 8 KiB,  [m][kk] swizzled
  const int tid = threadIdx.x;
  const int wave = tid >> 6, lane = tid & 63;
  const int base = blockIdx.x * MT;

  if (tid < MT) {
    const int pt = base + tid;
    const int b = pt >> 14;
    const int seg = (b << 11) + cid[pt];
    const float c = fmaxf(segacc[seg], 1.0f);
    const float x = pos[pt * 3 + 0] - segacc[NSEG + seg] / c;
    const float y = pos[pt * 3 + 1] - segacc[2 * NSEG + seg] / c;
    const float z = pos[pt * 3 + 2] - segacc[3 * NSEG + seg] / c;
    lps[tid][0] = x; lps[tid][1] = y; lps[tid][2] = z;
    lps[tid][3] = sqrtf(x * x + y * y + z * z);
  }
  // (first __syncthreads inside gemm_phase covers lps visibility)
  gemm_phase<4>(tid, wave, lane, base, lps, As, Bs,
                w1, b1, wt2, b2, feat, out);
  gemm_phase<3>(tid, wave, lane, base, lps, As, Bs,
                w3 + 3 * DD, b3, wt4, b4, feat, out + HGEO_OFF);
}

extern "C" void kernel_launch(void* const* d_in, const int* in_sizes, int n_in,
                              void* d_out, int out_size, void* d_ws, size_t ws_size,
                              hipStream_t stream) {
  const float* pos  = (const float*)d_in[0];
  const float* feat = (const float*)d_in[1];
  const int*   cid  = (const int*)d_in[2];
  const float* w1 = (const float*)d_in[3];
  const float* b1 = (const float*)d_in[4];
  const float* w2 = (const float*)d_in[5];
  const float* b2 = (const float*)d_in[6];
  const float* w3 = (const float*)d_in[7];
  const float* b3 = (const float*)d_in[8];
  const float* w4 = (const float*)d_in[9];
  const float* b4 = (const float*)d_in[10];
  float* out = (float*)d_out;

  char* ws = (char*)d_ws;
  float* segacc = (float*)ws;                                   // 128 KiB
  __hip_bfloat16* wt2 = (__hip_bfloat16*)(ws + (4 * NSEG) * 4); // 512 KiB
  __hip_bfloat16* wt4 = wt2 + DD * DD;                          // 512 KiB

  hipMemsetAsync(segacc, 0, 4 * NSEG * sizeof(float), stream);
  seg_sum_kernel<<<NPTS / 256, 256, 0, stream>>>(pos, cid, segacc);
  wt_cvt<<<512, 256, 0, stream>>>(w2, w4, wt2, wt4);
  lpe_mfma<<<NPTS / MT, 256, 0, stream>>>(pos, feat, cid,
                                          w1, b1, b2, w3, b3, b4,
                                          segacc, wt2, wt4, out);
}